// Round 4
// baseline (69.891 us; speedup 1.0000x reference)
//
#include <hip/hip_runtime.h>

// MelMeanFilteredMSE: out = mean( (M @ (10^(mo/10) - 10^(tg/10)))^2 )
// M is a banded variable-width mean filter (width <= 21, band monotone).
// Sliding-window running sum along frequency; one pass over 268 MB inputs.
// R3: chunk-of-4 row processing with 3-buffer register pipeline (loads
// issued 2 chunks = 8 rows ahead) to fix the latency-bound stall seen in
// R2 (1.45 TB/s, VALUBusy 15%). Ring/emission logic unchanged.

#define F 1025
#define TT 2048
#define BB 16
#define NSEG 12
#define SEG 86            // ceil(F / NSEG)
#define RING 24           // >= max live window span (<=22), proven from mel construction
#define TPB 256
#define TCH 512           // columns per block (float2 per thread)
#define NTB (TT / TCH)    // 4
#define NBLK (BB * NTB * NSEG)  // 768 = 3 blocks/CU exactly
#define CHUNK 4

// ---- kernel 1: extract band (start, end, 1/width) from the transform matrix.
__global__ __launch_bounds__(256) void band_kernel(const float* __restrict__ mtx,
                                                   int* __restrict__ bs,
                                                   int* __restrict__ be,
                                                   float* __restrict__ binv) {
    int row  = blockIdx.x * 4 + (threadIdx.x >> 6);
    int lane = threadIdx.x & 63;
    if (row >= F) return;                      // wave-uniform exit
    const float* r = mtx + (size_t)row * F;
    int first = -1, last = -1;
    for (int c = 0; c < (F + 63) / 64; ++c) {
        int j = c * 64 + lane;
        float v = (j < F) ? r[j] : 0.0f;
        unsigned long long m = __ballot(v != 0.0f);
        if (m) {
            if (first < 0) first = c * 64 + (__ffsll((unsigned long long)m) - 1);
            last = c * 64 + (63 - __clzll((long long)m));
        }
    }
    if (lane == 0) {
        bs[row]   = first;
        be[row]   = last + 1;
        binv[row] = r[first];                  // matrix stores 1/(end-start)
    }
}

// ---- kernel 2: main pass.
__global__ __launch_bounds__(TPB) void mel_mse_kernel(const float* __restrict__ mo,
                                                      const float* __restrict__ tg,
                                                      const int* __restrict__ bs,
                                                      const int* __restrict__ be,
                                                      const float* __restrict__ binv,
                                                      double* __restrict__ partial) {
    const int tid = threadIdx.x;
    const int blk = blockIdx.x;
    const int s  = blk % NSEG;
    const int r_ = blk / NSEG;
    const int tb = r_ % NTB;
    const int b  = r_ / NTB;

    const int i0 = s * SEG;
    const int i1 = (i0 + SEG < F) ? (i0 + SEG) : F;
    const int nrows = i1 - i0;

    __shared__ float2 ring[RING * TPB];        // 48 KB
    __shared__ int    be_l[SEG];
    __shared__ int    bs_l[SEG];
    __shared__ float  binv_l[SEG];

    if (tid < nrows) {
        be_l[tid]   = be[i0 + tid];
        bs_l[tid]   = bs[i0 + tid];
        binv_l[tid] = binv[i0 + tid];
    }
    __syncthreads();

    const int jstart = bs_l[0];
    const int jend   = be_l[nrows - 1];

    const int ct = tb * TPB + tid;             // float2 column index [0, TT/2)
    const float2* __restrict__ moP = (const float2*)(mo + (size_t)b * F * TT) + ct;
    const float2* __restrict__ tgP = (const float2*)(tg + (size_t)b * F * TT) + ct;
    const size_t rs = TT / 2;                  // row stride in float2

    const float C = 0.33219281f;               // log2(10)/10

    // 3-buffer chunk pipeline: A0 = rows j..j+3 (ready), A1 = j+4.., A2 = j+8..
    float2 A0[CHUNK], G0[CHUNK], A1[CHUNK], G1[CHUNK], A2[CHUNK], G2[CHUNK];

#define LOADC(Ad, Gd, jbase)                                        \
    _Pragma("unroll")                                               \
    for (int r = 0; r < CHUNK; ++r) {                               \
        int jr = (jbase) + r;                                       \
        jr = (jr < jend) ? jr : (jend - 1);                         \
        Ad[r] = moP[(size_t)jr * rs];                               \
        Gd[r] = tgP[(size_t)jr * rs];                               \
    }

    LOADC(A0, G0, jstart)
    LOADC(A1, G1, jstart + CHUNK)

    float wx = 0.0f, wy = 0.0f, acc = 0.0f;
    int i = 0, cs = jstart, wp = 0, rp = 0;

    for (int j = jstart; j < jend; j += CHUNK) {
        LOADC(A2, G2, j + 2 * CHUNK)           // issue 2 chunks (8 rows) ahead
        #pragma unroll
        for (int r = 0; r < CHUNK; ++r) {
            if (j + r < jend) {                // scalar-uniform guard
                const float dx = __builtin_amdgcn_exp2f(A0[r].x * C)
                               - __builtin_amdgcn_exp2f(G0[r].x * C);
                const float dy = __builtin_amdgcn_exp2f(A0[r].y * C)
                               - __builtin_amdgcn_exp2f(G0[r].y * C);
                float2 dv; dv.x = dx; dv.y = dy;
                ring[wp + tid] = dv;
                wp += TPB; if (wp == RING * TPB) wp = 0;
                wx += dx; wy += dy;
                while (i < nrows && be_l[i] <= j + r + 1) {
                    const int si = bs_l[i];
                    while (cs < si) {          // shrink window from below
                        const float2 o = ring[rp + tid];
                        rp += TPB; if (rp == RING * TPB) rp = 0;
                        wx -= o.x; wy -= o.y;
                        ++cs;
                    }
                    const float inv = binv_l[i];
                    const float fx = wx * inv, fy = wy * inv;
                    acc = fmaf(fx, fx, fmaf(fy, fy, acc));
                    ++i;
                }
            }
        }
        #pragma unroll
        for (int r = 0; r < CHUNK; ++r) {      // rotate buffers (static idx)
            A0[r] = A1[r]; G0[r] = G1[r];
            A1[r] = A2[r]; G1[r] = G2[r];
        }
    }
#undef LOADC

    // block reduction (float within wave, double across waves)
    #pragma unroll
    for (int off = 32; off > 0; off >>= 1)
        acc += __shfl_down(acc, off, 64);

    __shared__ double wred[4];
    const int wid = tid >> 6, lane = tid & 63;
    if (lane == 0) wred[wid] = (double)acc;
    __syncthreads();
    if (tid == 0)
        partial[blk] = wred[0] + wred[1] + wred[2] + wred[3];
}

// ---- kernel 3: final reduction -> scalar mean
__global__ __launch_bounds__(256) void final_kernel(const double* __restrict__ partial,
                                                    float* __restrict__ out) {
    const int tid = threadIdx.x;
    double s = 0.0;
    for (int k = tid; k < NBLK; k += 256) s += partial[k];
    #pragma unroll
    for (int off = 32; off > 0; off >>= 1)
        s += __shfl_down(s, off, 64);
    __shared__ double wred[4];
    const int wid = tid >> 6, lane = tid & 63;
    if (lane == 0) wred[wid] = s;
    __syncthreads();
    if (tid == 0) {
        double tot = wred[0] + wred[1] + wred[2] + wred[3];
        out[0] = (float)(tot / ((double)BB * (double)F * (double)TT));
    }
}

extern "C" void kernel_launch(void* const* d_in, const int* in_sizes, int n_in,
                              void* d_out, int out_size, void* d_ws, size_t ws_size,
                              hipStream_t stream) {
    const float* mo  = (const float*)d_in[0];
    const float* tg  = (const float*)d_in[1];
    const float* mtx = (const float*)d_in[2];

    char* ws = (char*)d_ws;
    int*    bs      = (int*)(ws);              // 1025 ints
    int*    be      = (int*)(ws + 8192);       // 1025 ints
    float*  binv    = (float*)(ws + 16384);    // 1025 floats
    double* partial = (double*)(ws + 24576);   // 768 doubles

    band_kernel<<<(F + 3) / 4, 256, 0, stream>>>(mtx, bs, be, binv);
    mel_mse_kernel<<<NBLK, TPB, 0, stream>>>(mo, tg, bs, be, binv, partial);
    final_kernel<<<1, 256, 0, stream>>>(partial, (float*)d_out);
}